// Round 4
// baseline (165.637 us; speedup 1.0000x reference)
//
#include <hip/hip_runtime.h>
#include <stdint.h>

#define BSZ   16
#define LSEQ  4096
#define HDIM  128
#define PDIM  256
#define TCH   32
#define CHUNKS (LSEQ/TCH)   // 128

typedef __attribute__((ext_vector_type(4)))  float  f32x4;
typedef __attribute__((ext_vector_type(16))) float  f32x16;
typedef __attribute__((ext_vector_type(8)))  __bf16 bf16x8;

// ---------------- workspace layout (bytes) ----------------
constexpr size_t WS_COEF  = 0;                                   // 6*256 floats
constexpr size_t WS_MPOW2 = 8192;                                // 7*4*256 floats
constexpr size_t WS_WB    = 40960;                               // 128 KB frag-packed Wb (32x32x16 tiles)
constexpr size_t WS_WC    = WS_WB + 131072;                      // 128 KB frag-packed Wc (16x16x32 tiles)
constexpr size_t WS_ENDS  = WS_WC + 131072;                      // 2 planes * 16*128*256 float2 = 8 MB
constexpr size_t PLANE    = (size_t)BSZ * CHUNKS * PDIM;         // float2 elems per plane
constexpr size_t WS_CARR  = WS_ENDS + 2 * PLANE * 8;             // 8 MB

__device__ __forceinline__ unsigned short f2bf(float f) {
  unsigned u = __float_as_uint(f);
  u = (u + 0x7fffu + ((u >> 16) & 1u)) >> 16;   // RNE
  return (unsigned short)u;
}

__device__ __forceinline__ bf16x8 cvt8(float4 f0, float4 f1v) {
  bf16x8 a;
  a[0]=(__bf16)f0.x;  a[1]=(__bf16)f0.y;  a[2]=(__bf16)f0.z;  a[3]=(__bf16)f0.w;
  a[4]=(__bf16)f1v.x; a[5]=(__bf16)f1v.y; a[6]=(__bf16)f1v.z; a[7]=(__bf16)f1v.w;
  return a;
}

// ---------------- K1: per-p coefficients + M^(32*2^j) powers ----------------
__global__ void coeff_kernel(const float* __restrict__ A_diag,
                             const float* __restrict__ G_diag,
                             const float* __restrict__ dtp,
                             float* __restrict__ coef,
                             float* __restrict__ mpow2) {
  int p = threadIdx.x;
  float dt_s = 1.0f / (1.0f + expf(-dtp[p]));
  float A = fmaxf(A_diag[p], 0.0f);
  float G = fmaxf(G_diag[p], 0.0f);
  float root  = sqrtf(1.0f + dt_s * G);
  float denom = fmaxf(dt_s * dt_s, 1e-6f);
  float A_low  = (2.0f + dt_s * G - 2.0f * root) / denom;
  float A_high = (2.0f + dt_s * G + 2.0f * root) / denom;
  A = A_low + fmaxf(A - A_low, 0.0f) - fmaxf(A - A_high, 0.0f);
  float S  = 1.0f / (1.0f + dt_s * G);
  float mA = S;
  float mB = -A * dt_s * S;
  float mC = dt_s * S;
  float mD = 1.0f - A * dt_s * dt_s * S;
  coef[0*PDIM + p] = mA;
  coef[1*PDIM + p] = mB;
  coef[2*PDIM + p] = mC;
  coef[3*PDIM + p] = mD;
  coef[4*PDIM + p] = dt_s;
  coef[5*PDIM + p] = mC;   // f1 scale = dt_s*S == mC
  float a = mA, b = mB, c = mC, d = mD;
  #pragma unroll
  for (int i = 0; i < 5; i++) {   // -> M^32
    float na = a*a + b*c, nb = a*b + b*d, nc = c*a + d*c, nd = c*b + d*d;
    a = na; b = nb; c = nc; d = nd;
  }
  mpow2[(0*4+0)*PDIM + p] = a; mpow2[(0*4+1)*PDIM + p] = b;
  mpow2[(0*4+2)*PDIM + p] = c; mpow2[(0*4+3)*PDIM + p] = d;
  #pragma unroll
  for (int j = 1; j < 7; j++) {
    float na = a*a + b*c, nb = a*b + b*d, nc = c*a + d*c, nd = c*b + d*d;
    a = na; b = nb; c = nc; d = nd;
    mpow2[(j*4+0)*PDIM + p] = a; mpow2[(j*4+1)*PDIM + p] = b;
    mpow2[(j*4+2)*PDIM + p] = c; mpow2[(j*4+3)*PDIM + p] = d;
  }
}

// ---------------- K1b: pack weights in MFMA fragment order ----------------
// Wb (32x32x16 B-frag): tiles ct(16) x kt(8); lane l: col=ct*32+(l&31), k=kt*16+(l>>5)*8+e (k=h)
// Wc (16x16x32 B-frag): tiles ct(8) x kt(16); lane l: col=ct*16+(l&15), k=kt*32+(l>>4)*8+e (k=p+256c)
__global__ __launch_bounds__(256) void prep_kernel(const float* __restrict__ B,
                                                   const float* __restrict__ C,
                                                   const float* __restrict__ coef,
                                                   ushort* __restrict__ Wb,
                                                   ushort* __restrict__ Wc) {
  int idx = blockIdx.x * 256 + threadIdx.x;   // 0..131071
  if (idx < 65536) {
    int e  = idx & 7;
    int l  = (idx >> 3) & 63;
    int kt = (idx >> 9) & 7;
    int ct = idx >> 12;                 // 0..15
    int k   = kt*16 + (l >> 5)*8 + e;   // h, 0..127
    int col = ct*32 + (l & 31);         // 0..511
    int c = col >> 8, p = col & 255;
    float f1 = coef[5*PDIM + p];
    Wb[idx] = f2bf(B[(size_t)p*2*HDIM + k*2 + c] * f1);
  } else {
    int j  = idx - 65536;
    int e  = j & 7;
    int l  = (j >> 3) & 63;
    int kt = (j >> 9) & 15;
    int ct = j >> 13;                   // 0..7
    int k = kt*32 + (l >> 4)*8 + e;     // 0..511
    int h = ct*16 + (l & 15);
    int c = k >> 8, p = k & 255;
    float v = C[(size_t)h*2*PDIM + p*2 + c];
    Wc[j] = f2bf(c ? -v : v);
  }
}

// ---------------- K_A: bu-GEMM (32x32x16, direct-global A) + register scan -> ends ----------------
// Wave w owns p-groups ga=2w, gb=2w+1 (cols w*64 .. w*64+63) for re and im tiles.
__global__ __launch_bounds__(256) void ka_kernel(const float* __restrict__ u,
                                                 const ushort* __restrict__ Wb,
                                                 const float* __restrict__ coef,
                                                 float2* __restrict__ ends2) {
  int tid = threadIdx.x;
  int l = tid & 63, w = tid >> 6;
  int l31 = l & 31, hi = l >> 5;
  int c = blockIdx.x, b = blockIdx.y;
  size_t row0 = (size_t)b * LSEQ + (size_t)c * TCH;

  f32x16 accRa = {}, accRb = {}, accIa = {}, accIb = {};
  const float* abase = u + (row0 + l31) * HDIM + hi * 8;
  const ushort* wbb = Wb + (size_t)l * 8;
  #pragma unroll
  for (int kt = 0; kt < 8; kt++) {
    float4 f0  = *(const float4*)(abase + kt*16);
    float4 f1v = *(const float4*)(abase + kt*16 + 4);
    bf16x8 a = cvt8(f0, f1v);
    bf16x8 bRa = *(const bf16x8*)(wbb + ((2*w    )*8 + kt)*512);
    bf16x8 bRb = *(const bf16x8*)(wbb + ((2*w + 1)*8 + kt)*512);
    bf16x8 bIa = *(const bf16x8*)(wbb + ((2*w + 8)*8 + kt)*512);
    bf16x8 bIb = *(const bf16x8*)(wbb + ((2*w + 9)*8 + kt)*512);
    accRa = __builtin_amdgcn_mfma_f32_32x32x16_bf16(a, bRa, accRa, 0, 0, 0);
    accRb = __builtin_amdgcn_mfma_f32_32x32x16_bf16(a, bRb, accRb, 0, 0, 0);
    accIa = __builtin_amdgcn_mfma_f32_32x32x16_bf16(a, bIa, accIa, 0, 0, 0);
    accIb = __builtin_amdgcn_mfma_f32_32x32x16_bf16(a, bIb, accIb, 0, 0, 0);
  }

  // exchange: hi=0 lanes scan RE, hi=1 lanes scan IM (independent recurrences)
  float s0a[16], s1a[16], s0b[16], s1b[16];
  #pragma unroll
  for (int r = 0; r < 16; r++) {
    float ya = hi ? accRa[r] : accIa[r];
    float Oa = __shfl_xor(ya, 32);
    float Ma = hi ? accIa[r] : accRa[r];
    s0a[r] = hi ? Oa : Ma;
    s1a[r] = hi ? Ma : Oa;
    float yb = hi ? accRb[r] : accIb[r];
    float Ob = __shfl_xor(yb, 32);
    float Mb = hi ? accIb[r] : accRb[r];
    s0b[r] = hi ? Ob : Mb;
    s1b[r] = hi ? Mb : Ob;
  }

  int pa = w*64 + l31, pb = pa + 32;
  float mAa = coef[pa], mBa = coef[256+pa], mCa = coef[512+pa], mDa = coef[768+pa], dsa = coef[1024+pa];
  float mAb = coef[pb], mBb = coef[256+pb], mCb = coef[512+pb], mDb = coef[768+pb], dsb = coef[1024+pb];

  float v1a = 0.f, v2a = 0.f, v1b = 0.f, v2b = 0.f;
  #pragma unroll
  for (int t = 0; t < 32; t++) {
    const int r = (t & 3) | ((t >> 3) << 2);
    float fa = ((t >> 2) & 1) ? s1a[r] : s0a[r];
    float fb = ((t >> 2) & 1) ? s1b[r] : s0b[r];
    float n1a = fmaf(mAa, v1a, fmaf(mBa, v2a, fa));
    float n2a = fmaf(mCa, v1a, fmaf(mDa, v2a, dsa * fa));
    float n1b = fmaf(mAb, v1b, fmaf(mBb, v2b, fb));
    float n2b = fmaf(mCb, v1b, fmaf(mDb, v2b, dsb * fb));
    v1a = n1a; v2a = n2a; v1b = n1b; v2b = n2b;
  }

  size_t ebase = (size_t)hi * PLANE + ((size_t)b * CHUNKS + c) * PDIM;
  ends2[ebase + pa] = make_float2(v1a, v2a);
  ends2[ebase + pb] = make_float2(v1b, v2b);
}

// ---------------- K_carry: Kogge-Stone over 128 chunks, SoA re/im planes ----------------
__global__ __launch_bounds__(256) void carry_kernel(const float2* __restrict__ ends2,
                                                    const float* __restrict__ mpow2,
                                                    float2* __restrict__ carr2) {
  __shared__ float2 buf[2][CHUNKS];
  int tid = threadIdx.x;
  int c = tid >> 1, pi = tid & 1;
  int b = blockIdx.x, y = blockIdx.y;
  int plane = y >> 7, pg = y & 127;
  int p = pg * 2 + pi;
  size_t base = (size_t)plane * PLANE + (size_t)b * CHUNKS * PDIM + p;
  float2 v = ends2[base + (size_t)c * PDIM];
  buf[pi][c] = v;
  __syncthreads();
  #pragma unroll
  for (int j = 0; j < 7; j++) {
    int d = 1 << j;
    bool act = (c >= d);
    float2 s;
    if (act) s = buf[pi][c - d];
    __syncthreads();
    if (act) {
      float qA = mpow2[(j*4+0)*PDIM + p], qB = mpow2[(j*4+1)*PDIM + p];
      float qC = mpow2[(j*4+2)*PDIM + p], qD = mpow2[(j*4+3)*PDIM + p];
      float nx = fmaf(qA, s.x, fmaf(qB, s.y, v.x));
      float ny = fmaf(qC, s.x, fmaf(qD, s.y, v.y));
      v.x = nx; v.y = ny;
      buf[pi][c] = v;
    }
    __syncthreads();
  }
  float2 cv = (c == 0) ? make_float2(0.f, 0.f) : buf[pi][c - 1];
  carr2[base + (size_t)c * PDIM] = cv;
}

// ---------------- K_B: bu-GEMM + carry-in register scan -> xst LDS -> out-GEMM ----------------
__global__ __launch_bounds__(256, 3) void kb_kernel(const float* __restrict__ u,
                                                    const ushort* __restrict__ Wb,
                                                    const ushort* __restrict__ Wc,
                                                    const float* __restrict__ coef,
                                                    const float2* __restrict__ carr2,
                                                    const float* __restrict__ Dv,
                                                    float* __restrict__ out) {
  __shared__ ushort xst[TCH][520];   // xs rows [t][p | p+256], 33.3 KB
  int tid = threadIdx.x;
  int l = tid & 63, w = tid >> 6;
  int l31 = l & 31, hi = l >> 5;
  int lr = l & 15, lk = (l >> 4) & 3;
  int c = blockIdx.x, b = blockIdx.y;
  size_t row0 = (size_t)b * LSEQ + (size_t)c * TCH;

  // ---- bu GEMM (32x32x16), A-frags direct from global ----
  f32x16 accRa = {}, accRb = {}, accIa = {}, accIb = {};
  const float* abase = u + (row0 + l31) * HDIM + hi * 8;
  const ushort* wbb = Wb + (size_t)l * 8;
  #pragma unroll
  for (int kt = 0; kt < 8; kt++) {
    float4 f0  = *(const float4*)(abase + kt*16);
    float4 f1v = *(const float4*)(abase + kt*16 + 4);
    bf16x8 a = cvt8(f0, f1v);
    bf16x8 bRa = *(const bf16x8*)(wbb + ((2*w    )*8 + kt)*512);
    bf16x8 bRb = *(const bf16x8*)(wbb + ((2*w + 1)*8 + kt)*512);
    bf16x8 bIa = *(const bf16x8*)(wbb + ((2*w + 8)*8 + kt)*512);
    bf16x8 bIb = *(const bf16x8*)(wbb + ((2*w + 9)*8 + kt)*512);
    accRa = __builtin_amdgcn_mfma_f32_32x32x16_bf16(a, bRa, accRa, 0, 0, 0);
    accRb = __builtin_amdgcn_mfma_f32_32x32x16_bf16(a, bRb, accRb, 0, 0, 0);
    accIa = __builtin_amdgcn_mfma_f32_32x32x16_bf16(a, bIa, accIa, 0, 0, 0);
    accIb = __builtin_amdgcn_mfma_f32_32x32x16_bf16(a, bIb, accIb, 0, 0, 0);
  }

  // ---- exchange ----
  float s0a[16], s1a[16], s0b[16], s1b[16];
  #pragma unroll
  for (int r = 0; r < 16; r++) {
    float ya = hi ? accRa[r] : accIa[r];
    float Oa = __shfl_xor(ya, 32);
    float Ma = hi ? accIa[r] : accRa[r];
    s0a[r] = hi ? Oa : Ma;
    s1a[r] = hi ? Ma : Oa;
    float yb = hi ? accRb[r] : accIb[r];
    float Ob = __shfl_xor(yb, 32);
    float Mb = hi ? accIb[r] : accRb[r];
    s0b[r] = hi ? Ob : Mb;
    s1b[r] = hi ? Mb : Ob;
  }

  // ---- scan with carry-in; emit xs to LDS ----
  int pa = w*64 + l31, pb = pa + 32;
  float mAa = coef[pa], mBa = coef[256+pa], mCa = coef[512+pa], mDa = coef[768+pa], dsa = coef[1024+pa];
  float mAb = coef[pb], mBb = coef[256+pb], mCb = coef[512+pb], mDb = coef[768+pb], dsb = coef[1024+pb];
  size_t cbase = (size_t)hi * PLANE + ((size_t)b * CHUNKS + c) * PDIM;
  float2 cva = carr2[cbase + pa];
  float2 cvb = carr2[cbase + pb];
  float v1a = cva.x, v2a = cva.y, v1b = cvb.x, v2b = cvb.y;
  int cola = pa + (hi << 8);
  int colb = pb + (hi << 8);
  #pragma unroll
  for (int t = 0; t < 32; t++) {
    const int r = (t & 3) | ((t >> 3) << 2);
    float fa = ((t >> 2) & 1) ? s1a[r] : s0a[r];
    float fb = ((t >> 2) & 1) ? s1b[r] : s0b[r];
    float n1a = fmaf(mAa, v1a, fmaf(mBa, v2a, fa));
    float n2a = fmaf(mCa, v1a, fmaf(mDa, v2a, dsa * fa));
    float n1b = fmaf(mAb, v1b, fmaf(mBb, v2b, fb));
    float n2b = fmaf(mCb, v1b, fmaf(mDb, v2b, dsb * fb));
    v1a = n1a; v2a = n2a; v1b = n1b; v2b = n2b;
    xst[t][cola] = f2bf(v2a);
    xst[t][colb] = f2bf(v2b);
  }
  __syncthreads();

  // ---- out GEMM (16x16x32): wave w -> ct {2w,2w+1}, rt {0,1}; Wc read once per block ----
  f32x4 oacc00 = {}, oacc01 = {}, oacc10 = {}, oacc11 = {};
  #pragma unroll
  for (int kt = 0; kt < 16; kt++) {
    bf16x8 af0 = *(const bf16x8*)&xst[lr][kt*32 + lk*8];
    bf16x8 af1 = *(const bf16x8*)&xst[16 + lr][kt*32 + lk*8];
    bf16x8 b0 = *(const bf16x8*)(Wc + (((size_t)(2*w    )*16 + kt)*64 + l)*8);
    bf16x8 b1 = *(const bf16x8*)(Wc + (((size_t)(2*w + 1)*16 + kt)*64 + l)*8);
    oacc00 = __builtin_amdgcn_mfma_f32_16x16x32_bf16(af0, b0, oacc00, 0, 0, 0);
    oacc01 = __builtin_amdgcn_mfma_f32_16x16x32_bf16(af1, b0, oacc01, 0, 0, 0);
    oacc10 = __builtin_amdgcn_mfma_f32_16x16x32_bf16(af0, b1, oacc10, 0, 0, 0);
    oacc11 = __builtin_amdgcn_mfma_f32_16x16x32_bf16(af1, b1, oacc11, 0, 0, 0);
  }
  #pragma unroll
  for (int i = 0; i < 2; i++) {
    int h = (2*w + i)*16 + lr;
    float Dh = Dv[h];
    f32x4 a0 = i ? oacc10 : oacc00;
    f32x4 a1 = i ? oacc11 : oacc01;
    #pragma unroll
    for (int r = 0; r < 4; r++) {
      int t0 = lk*4 + r;
      size_t idx0 = (row0 + t0) * HDIM + h;
      out[idx0] = a0[r] + Dh * u[idx0];
      size_t idx1 = (row0 + 16 + t0) * HDIM + h;
      out[idx1] = a1[r] + Dh * u[idx1];
    }
  }
}

extern "C" void kernel_launch(void* const* d_in, const int* in_sizes, int n_in,
                              void* d_out, int out_size, void* d_ws, size_t ws_size,
                              hipStream_t stream) {
  const float* u      = (const float*)d_in[0];
  const float* A_diag = (const float*)d_in[1];
  const float* G_diag = (const float*)d_in[2];
  const float* dt     = (const float*)d_in[3];
  const float* B      = (const float*)d_in[4];
  const float* C      = (const float*)d_in[5];
  const float* D      = (const float*)d_in[6];
  float* out = (float*)d_out;

  char* ws = (char*)d_ws;
  float*  coef  = (float*)(ws + WS_COEF);
  float*  mpow2 = (float*)(ws + WS_MPOW2);
  ushort* Wb    = (ushort*)(ws + WS_WB);
  ushort* Wc    = (ushort*)(ws + WS_WC);
  float2* ends2 = (float2*)(ws + WS_ENDS);
  float2* carr2 = (float2*)(ws + WS_CARR);

  hipLaunchKernelGGL(coeff_kernel, dim3(1), dim3(PDIM), 0, stream, A_diag, G_diag, dt, coef, mpow2);
  hipLaunchKernelGGL(prep_kernel, dim3(512), dim3(256), 0, stream, B, C, coef, Wb, Wc);
  hipLaunchKernelGGL(ka_kernel, dim3(CHUNKS, BSZ), dim3(256), 0, stream, u, Wb, coef, ends2);
  hipLaunchKernelGGL(carry_kernel, dim3(BSZ, 2*CHUNKS), dim3(256), 0, stream, ends2, mpow2, carr2);
  hipLaunchKernelGGL(kb_kernel, dim3(CHUNKS, BSZ), dim3(256), 0, stream, u, Wb, Wc, coef, carr2, D, out);
}